// Round 1
// baseline (2630.198 us; speedup 1.0000x reference)
//
#include <hip/hip_runtime.h>
#include <cstdint>
#include <cstddef>

#define NN    20000
#define EM    100000
#define EBN   20000
#define WID   32
#define KW    64
#define KIN   6
#define NDEPTH 4

// ---------------- small setup kernels ----------------

__global__ void k_prep(const float* __restrict__ r1, const float* __restrict__ b1,
                       const float* __restrict__ r2, const float* __restrict__ b2,
                       float* __restrict__ rs, float* __restrict__ bs) {
    int i = threadIdx.x;
    if (i < 1024) rs[i] = r1[i] + r2[i];
    if (i < 32)   bs[i] = b1[i] + b2[i];
}

__global__ void k_h0(const float* __restrict__ x, const float* __restrict__ fc1w,
                     const float* __restrict__ fc1b, float* __restrict__ h0,
                     float* __restrict__ h) {
    int t = blockIdx.x * blockDim.x + threadIdx.x;
    if (t >= NN * WID) return;
    int node = t >> 5, j = t & 31;
    float v = x[node] * fc1w[j] + fc1b[j];
    h0[t] = v; h[t] = v;
}

__global__ void k_count(const int* __restrict__ dst, int E, int* __restrict__ cnt) {
    int e = blockIdx.x * blockDim.x + threadIdx.x;
    if (e < E) atomicAdd(&cnt[dst[e]], 1);
}

__global__ void k_inv(const int* __restrict__ cnt, float* __restrict__ inv, int n) {
    int i = blockIdx.x * blockDim.x + threadIdx.x;
    if (i < n) {
        int c = cnt[i]; if (c < 1) c = 1;
        inv[i] = 1.0f / (float)c;
    }
}

// ---------------- edge MLP: ea(E x 6) -> K(E x 64) ----------------

__global__ __launch_bounds__(256) void k_mlp(const float* __restrict__ ea, int E,
        const float* __restrict__ w1, const float* __restrict__ b1,
        const float* __restrict__ w2, const float* __restrict__ b2,
        float* __restrict__ K) {
    __shared__ float sw1[KIN * KW];   // 1.5 KB
    __shared__ float sw2[KW * KW];    // 16 KB
    __shared__ float sb1[KW];
    __shared__ float sb2[KW];
    for (int i = threadIdx.x; i < KIN * KW; i += 256) sw1[i] = w1[i];
    for (int i = threadIdx.x; i < KW * KW; i += 256)  sw2[i] = w2[i];
    if (threadIdx.x < KW) { sb1[threadIdx.x] = b1[threadIdx.x]; sb2[threadIdx.x] = b2[threadIdx.x]; }
    __syncthreads();
    int e = blockIdx.x * 256 + threadIdx.x;
    if (e >= E) return;
    float a[KIN];
#pragma unroll
    for (int i = 0; i < KIN; i++) a[i] = ea[(size_t)e * KIN + i];
    float t[KW];
#pragma unroll 8
    for (int j = 0; j < KW; j++) {
        float s = sb1[j];
#pragma unroll
        for (int i = 0; i < KIN; i++) s += a[i] * sw1[i * KW + j];
        t[j] = fmaxf(s, 0.0f);
    }
#pragma unroll 4
    for (int j = 0; j < KW; j++) {
        float s = sb2[j];
#pragma unroll 16
        for (int c = 0; c < KW; c++) s += t[c] * sw2[c * KW + j];
        K[(size_t)e * KW + j] = fmaxf(s, 0.0f);
    }
}

// ---------------- W = K(E x 64) @ w3(64 x 1024) + b3, tiled fp32 GEMM ----------------
// tile: 32 edges x 128 cols, full K=64. block 256 = 8 row-groups x 32 col-threads.

__global__ __launch_bounds__(256) void k_wgen(const float* __restrict__ K, int E,
        const float* __restrict__ w3, const float* __restrict__ b3,
        float* __restrict__ W) {
    __shared__ float sK[32 * 64];    // 8 KB
    __shared__ float sW[64 * 128];   // 32 KB
    int e0 = blockIdx.x * 32;
    int c0 = blockIdx.y * 128;
    for (int i = threadIdx.x; i < 32 * 64; i += 256) {
        int r = i >> 6, c = i & 63;
        int e = e0 + r;
        sK[i] = (e < E) ? K[(size_t)e * 64 + c] : 0.0f;
    }
    for (int i = threadIdx.x; i < 64 * 128; i += 256) {
        int c = i >> 7, col = i & 127;
        sW[i] = w3[(size_t)c * 1024 + c0 + col];
    }
    __syncthreads();
    int lt = threadIdx.x & 31;   // cols lt*4 .. +3
    int rt = threadIdx.x >> 5;   // rows rt*4 .. +3
    float acc[4][4];
#pragma unroll
    for (int k = 0; k < 4; k++) {
        float bv = b3[c0 + lt * 4 + k];
        acc[0][k] = bv; acc[1][k] = bv; acc[2][k] = bv; acc[3][k] = bv;
    }
    for (int c = 0; c < 64; c += 4) {
        float4 kv[4];
#pragma unroll
        for (int r = 0; r < 4; r++) kv[r] = *(const float4*)&sK[(rt * 4 + r) * 64 + c];
#pragma unroll
        for (int cc = 0; cc < 4; cc++) {
            float4 wv = *(const float4*)&sW[(c + cc) * 128 + lt * 4];
#pragma unroll
            for (int r = 0; r < 4; r++) {
                float kf = (&kv[r].x)[cc];
                acc[r][0] += kf * wv.x; acc[r][1] += kf * wv.y;
                acc[r][2] += kf * wv.z; acc[r][3] += kf * wv.w;
            }
        }
    }
#pragma unroll
    for (int r = 0; r < 4; r++) {
        int e = e0 + rt * 4 + r;
        if (e < E) *(float4*)&W[(size_t)e * 1024 + c0 + lt * 4] = *(float4*)acc[r];
    }
}

// ---------------- per-depth: msg = h[src] @ W[e], atomic mean-aggregate ----------------
// 8 threads per edge, 4 outputs each, float4 W reads (coalesced streaming).

__global__ __launch_bounds__(256) void k_msg(const int* __restrict__ ei, int E,
        const float* __restrict__ h, const float* __restrict__ W,
        float* __restrict__ agg) {
    int t = blockIdx.x * 256 + threadIdx.x;
    int e = t >> 3;
    if (e >= E) return;
    int q = (t & 7) * 4;
    int src = ei[e], dst = ei[E + e];
    const float* hr = h + (size_t)src * WID;
    const float* We = W + (size_t)e * 1024 + q;
    float hrv[32];
#pragma unroll
    for (int i = 0; i < 8; i++) *(float4*)&hrv[i * 4] = *(const float4*)(hr + i * 4);
    float4 acc = make_float4(0.f, 0.f, 0.f, 0.f);
#pragma unroll
    for (int i = 0; i < 32; i++) {
        float hv = hrv[i];
        float4 w = *(const float4*)(We + i * 32);
        acc.x += hv * w.x; acc.y += hv * w.y; acc.z += hv * w.z; acc.w += hv * w.w;
    }
    float* ap = agg + (size_t)dst * WID + q;
    unsafeAtomicAdd(ap + 0, acc.x);
    unsafeAtomicAdd(ap + 1, acc.y);
    unsafeAtomicAdd(ap + 2, acc.z);
    unsafeAtomicAdd(ap + 3, acc.w);
}

// ---------------- fallback (lean ws): fused msg from K and w3 ----------------

__global__ __launch_bounds__(256) void k_msg_fused(const int* __restrict__ ei, int E,
        const float* __restrict__ h, const float* __restrict__ Kf,
        const float* __restrict__ w3, const float* __restrict__ b3,
        float* __restrict__ agg) {
    __shared__ float sw3[8 * 1024];  // 32 KB chunk of w3 rows
    int lane = threadIdx.x & 63;
    int wid  = threadIdx.x >> 6;
    int sub  = lane >> 5;
    int o    = lane & 31;
    int e = blockIdx.x * 8 + wid * 2 + sub;
    bool valid = (e < E);
    int ec = valid ? e : 0;
    int src = ei[ec];
    int dst = ei[E + ec];
    float hs[32];
#pragma unroll
    for (int i = 0; i < 32; i++) hs[i] = h[(size_t)src * WID + i];
    float msg = 0.0f;
#pragma unroll
    for (int i = 0; i < 32; i++) msg += hs[i] * b3[i * 32 + o];
    for (int cc = 0; cc < 64; cc += 8) {
        __syncthreads();
        for (int i = threadIdx.x; i < 8 * 1024; i += 256) sw3[i] = w3[(size_t)cc * 1024 + i];
        __syncthreads();
#pragma unroll
        for (int c = 0; c < 8; c++) {
            float s = 0.0f;
#pragma unroll
            for (int i = 0; i < 32; i++) s += hs[i] * sw3[c * 1024 + i * 32 + o];
            msg += Kf[(size_t)ec * KW + cc + c] * s;
        }
    }
    if (valid) unsafeAtomicAdd(&agg[(size_t)dst * WID + o], msg);
}

// ---------------- node update: mean + root-matmul + relu + residual ----------------

__global__ __launch_bounds__(256) void k_node(const float* __restrict__ hin,
        float* __restrict__ hout,
        const float* __restrict__ agg1, const float* __restrict__ aggb,
        const float* __restrict__ inv1, const float* __restrict__ invb,
        const float* __restrict__ h0, const float* __restrict__ rs,
        const float* __restrict__ bs) {
    __shared__ float sR[1024];
    __shared__ float sB[32];
    for (int i = threadIdx.x; i < 1024; i += 256) sR[i] = rs[i];
    if (threadIdx.x < 32) sB[threadIdx.x] = bs[threadIdx.x];
    __syncthreads();
    int t = blockIdx.x * 256 + threadIdx.x;
    if (t >= NN * WID) return;
    int n = t >> 5, j = t & 31;
    float s = agg1[t] * inv1[n] + aggb[t] * invb[n] + sB[j];
    const float* hr = hin + (size_t)n * WID;
#pragma unroll
    for (int i = 0; i < 32; i++) s += hr[i] * sR[i * 32 + j];
    hout[t] = fmaxf(s, 0.0f) + h0[t];
}

__global__ void k_fc2(const float* __restrict__ h, const float* __restrict__ w,
                      const float* __restrict__ b, float* __restrict__ out) {
    int n = blockIdx.x * blockDim.x + threadIdx.x;
    if (n >= NN) return;
    const float4* hv = (const float4*)(h + (size_t)n * WID);
    const float4* wv = (const float4*)w;
    float s = b[0];
#pragma unroll
    for (int q = 0; q < 8; q++) {
        float4 a = hv[q], c = wv[q];
        s += a.x * c.x + a.y * c.y + a.z * c.z + a.w * c.w;
    }
    out[n] = s;
}

// ---------------- launch ----------------

extern "C" void kernel_launch(void* const* d_in, const int* in_sizes, int n_in,
                              void* d_out, int out_size, void* d_ws, size_t ws_size,
                              hipStream_t stream) {
    const float* x    = (const float*)d_in[0];
    const int*   ei   = (const int*)d_in[1];
    const float* ea   = (const float*)d_in[2];
    const int*   eib  = (const int*)d_in[3];
    const float* eab  = (const float*)d_in[4];
    const float* fc1w = (const float*)d_in[5];
    const float* fc1b = (const float*)d_in[6];
    const float* fc2w = (const float*)d_in[7];
    const float* fc2b = (const float*)d_in[8];
    const float* k1w1 = (const float*)d_in[9];
    const float* k1b1 = (const float*)d_in[10];
    const float* k1w2 = (const float*)d_in[11];
    const float* k1b2 = (const float*)d_in[12];
    const float* k1w3 = (const float*)d_in[13];
    const float* k1b3 = (const float*)d_in[14];
    const float* root1= (const float*)d_in[15];
    const float* bias1= (const float*)d_in[16];
    const float* k2w1 = (const float*)d_in[17];
    const float* k2b1 = (const float*)d_in[18];
    const float* k2w2 = (const float*)d_in[19];
    const float* k2b2 = (const float*)d_in[20];
    const float* k2w3 = (const float*)d_in[21];
    const float* k2b3 = (const float*)d_in[22];
    const float* root2= (const float*)d_in[23];
    const float* bias2= (const float*)d_in[24];

    float* p = (float*)d_ws;
    auto alloc = [&](size_t nflt) { float* r = p; p += nflt; return r; };
    float* K1   = alloc((size_t)EM * KW);
    float* Kb   = alloc((size_t)EBN * KW);
    float* h0   = alloc((size_t)NN * WID);
    float* hA   = alloc((size_t)NN * WID);
    float* hB   = alloc((size_t)NN * WID);
    float* agg1 = alloc((size_t)NN * WID);
    float* aggb = alloc((size_t)NN * WID);
    float* inv1 = alloc(NN);
    float* invb = alloc(NN);
    float* rs   = alloc(1024);
    float* bs   = alloc(32);
    int*   cnt1 = (int*)alloc(NN);
    int*   cntb = (int*)alloc(NN);
    size_t lean_bytes = (size_t)((char*)p - (char*)d_ws);
    size_t full_bytes = lean_bytes + ((size_t)EM + EBN) * 1024 * sizeof(float);
    bool full = (ws_size >= full_bytes);
    float* W1 = p;
    float* Wb = p + (size_t)EM * 1024;

    hipMemsetAsync(cnt1, 0, NN * sizeof(int), stream);
    hipMemsetAsync(cntb, 0, NN * sizeof(int), stream);
    k_prep<<<1, 1024, 0, stream>>>(root1, bias1, root2, bias2, rs, bs);
    k_h0<<<(NN * WID + 255) / 256, 256, 0, stream>>>(x, fc1w, fc1b, h0, hA);
    k_count<<<(EM + 255) / 256, 256, 0, stream>>>(ei + EM, EM, cnt1);
    k_count<<<(EBN + 255) / 256, 256, 0, stream>>>(eib + EBN, EBN, cntb);
    k_inv<<<(NN + 255) / 256, 256, 0, stream>>>(cnt1, inv1, NN);
    k_inv<<<(NN + 255) / 256, 256, 0, stream>>>(cntb, invb, NN);
    k_mlp<<<(EM + 255) / 256, 256, 0, stream>>>(ea, EM, k1w1, k1b1, k1w2, k1b2, K1);
    k_mlp<<<(EBN + 255) / 256, 256, 0, stream>>>(eab, EBN, k2w1, k2b1, k2w2, k2b2, Kb);
    if (full) {
        k_wgen<<<dim3((EM + 31) / 32, 8), 256, 0, stream>>>(K1, EM, k1w3, k1b3, W1);
        k_wgen<<<dim3((EBN + 31) / 32, 8), 256, 0, stream>>>(Kb, EBN, k2w3, k2b3, Wb);
    }

    const float* hin = hA;
    float* hout = hB;
    for (int d = 0; d < NDEPTH; d++) {
        hipMemsetAsync(agg1, 0, (size_t)NN * WID * sizeof(float), stream);
        hipMemsetAsync(aggb, 0, (size_t)NN * WID * sizeof(float), stream);
        if (full) {
            k_msg<<<(EM * 8 + 255) / 256, 256, 0, stream>>>(ei, EM, hin, W1, agg1);
            k_msg<<<(EBN * 8 + 255) / 256, 256, 0, stream>>>(eib, EBN, hin, Wb, aggb);
        } else {
            k_msg_fused<<<(EM + 7) / 8, 256, 0, stream>>>(ei, EM, hin, K1, k1w3, k1b3, agg1);
            k_msg_fused<<<(EBN + 7) / 8, 256, 0, stream>>>(eib, EBN, hin, Kb, k2w3, k2b3, aggb);
        }
        k_node<<<(NN * WID + 255) / 256, 256, 0, stream>>>(hin, hout, agg1, aggb,
                                                           inv1, invb, h0, rs, bs);
        float* tmp = (float*)hin; hin = hout; hout = tmp;
    }
    k_fc2<<<(NN + 255) / 256, 256, 0, stream>>>(hin, fc2w, fc2b, (float*)d_out);
}

// Round 2
// 2625.167 us; speedup vs baseline: 1.0019x; 1.0019x over previous
//
#include <hip/hip_runtime.h>
#include <cstdint>
#include <cstddef>

#define NN    20000
#define EM    100000
#define EBN   20000
#define WID   32
#define KW    64
#define KIN   6
#define NDEPTH 4
#define GC    2080   // 64*32 kernel cols + 32 bias cols

// ---------------- small setup kernels ----------------

__global__ void k_prep(const float* __restrict__ r1, const float* __restrict__ b1,
                       const float* __restrict__ r2, const float* __restrict__ b2,
                       float* __restrict__ rs, float* __restrict__ bs) {
    int i = threadIdx.x;
    if (i < 1024) rs[i] = r1[i] + r2[i];
    if (i < 32)   bs[i] = b1[i] + b2[i];
}

__global__ void k_h0(const float* __restrict__ x, const float* __restrict__ fc1w,
                     const float* __restrict__ fc1b, float* __restrict__ h0,
                     float* __restrict__ h) {
    int t = blockIdx.x * blockDim.x + threadIdx.x;
    if (t >= NN * WID) return;
    int node = t >> 5, j = t & 31;
    float v = x[node] * fc1w[j] + fc1b[j];
    h0[t] = v; h[t] = v;
}

__global__ void k_count(const int* __restrict__ idx, int E, int* __restrict__ cnt) {
    int e = blockIdx.x * blockDim.x + threadIdx.x;
    if (e < E) atomicAdd(&cnt[idx[e]], 1);
}

__global__ void k_inv(const int* __restrict__ cnt, float* __restrict__ inv, int n) {
    int i = blockIdx.x * blockDim.x + threadIdx.x;
    if (i < n) {
        int c = cnt[i]; if (c < 1) c = 1;
        inv[i] = 1.0f / (float)c;
    }
}

// exclusive prefix sum of cnt[0..n) -> cur[0..n), single block 1024 threads
__global__ __launch_bounds__(1024) void k_scan(const int* __restrict__ cnt,
                                               int* __restrict__ cur, int n) {
    __shared__ int part[1024];
    int t = threadIdx.x;
    int per = (n + 1023) / 1024;
    int base = t * per;
    int s = 0;
    for (int i = 0; i < per; i++) { int idx = base + i; if (idx < n) s += cnt[idx]; }
    part[t] = s;
    __syncthreads();
    for (int off = 1; off < 1024; off <<= 1) {
        int v = (t >= off) ? part[t - off] : 0;
        __syncthreads();
        part[t] += v;
        __syncthreads();
    }
    int run = (t > 0) ? part[t - 1] : 0;
    for (int i = 0; i < per; i++) {
        int idx = base + i;
        if (idx < n) { cur[idx] = run; run += cnt[idx]; }
    }
}

__global__ void k_scatter(const int* __restrict__ src, int E,
                          int* __restrict__ cur, int* __restrict__ perm) {
    int e = blockIdx.x * blockDim.x + threadIdx.x;
    if (e < E) { int p = atomicAdd(&cur[src[e]], 1); perm[p] = e; }
}

__global__ void k_permidx(const int* __restrict__ ei, int E,
                          const int* __restrict__ perm,
                          int* __restrict__ src_s, int* __restrict__ dst_s) {
    int i = blockIdx.x * blockDim.x + threadIdx.x;
    if (i >= E) return;
    int e = perm[i];
    src_s[i] = ei[e];
    dst_s[i] = ei[E + e];
}

// M[i][c*32+o] = w3[c][i*32+o] (c<64); M[i][2048+o] = b3[i*32+o]
__global__ void k_permM(const float* __restrict__ w3, const float* __restrict__ b3,
                        float* __restrict__ M) {
    int t = blockIdx.x * blockDim.x + threadIdx.x;
    if (t >= 32 * GC) return;
    int i = t / GC, c = t % GC;
    if (c < 2048) {
        int cc = c >> 5, o = c & 31;
        M[t] = w3[cc * 1024 + i * 32 + o];
    } else {
        M[t] = b3[i * 32 + (c - 2048)];
    }
}

// ---------------- edge MLP: ea(E x 6) -> K(E x 64), optionally in sorted order ----------------

__global__ __launch_bounds__(256) void k_mlp(const float* __restrict__ ea, int E,
        const float* __restrict__ w1, const float* __restrict__ b1,
        const float* __restrict__ w2, const float* __restrict__ b2,
        const int* __restrict__ perm, float* __restrict__ K) {
    __shared__ float sw1[KIN * KW];
    __shared__ float sw2[KW * KW];
    __shared__ float sb1[KW];
    __shared__ float sb2[KW];
    for (int i = threadIdx.x; i < KIN * KW; i += 256) sw1[i] = w1[i];
    for (int i = threadIdx.x; i < KW * KW; i += 256)  sw2[i] = w2[i];
    if (threadIdx.x < KW) { sb1[threadIdx.x] = b1[threadIdx.x]; sb2[threadIdx.x] = b2[threadIdx.x]; }
    __syncthreads();
    int e = blockIdx.x * 256 + threadIdx.x;
    if (e >= E) return;
    int eo = perm ? perm[e] : e;
    float a[KIN];
#pragma unroll
    for (int i = 0; i < KIN; i++) a[i] = ea[(size_t)eo * KIN + i];
    float t[KW];
#pragma unroll 8
    for (int j = 0; j < KW; j++) {
        float s = sb1[j];
#pragma unroll
        for (int i = 0; i < KIN; i++) s += a[i] * sw1[i * KW + j];
        t[j] = fmaxf(s, 0.0f);
    }
#pragma unroll 4
    for (int j = 0; j < KW; j++) {
        float s = sb2[j];
#pragma unroll 16
        for (int c = 0; c < KW; c++) s += t[c] * sw2[c * KW + j];
        K[(size_t)e * KW + j] = fmaxf(s, 0.0f);
    }
}

// ---------------- per-depth GEMM: G(NN x GC) = H(NN x 32) @ M(32 x GC) ----------------
// block 256: tile 32 nodes x 128 cols; thread = 4 nodes x 4 cols (float4 accums)

__global__ __launch_bounds__(256) void k_geng(const float* __restrict__ h,
        const float* __restrict__ M, float* __restrict__ G) {
    __shared__ float sHt[32][32];   // [k][node]
    __shared__ float sM[32][128];   // [k][col]
    int n0 = blockIdx.x * 32;
    int c0 = blockIdx.y * 128;
    int t = threadIdx.x;
    {
        int nn = t >> 3, kg = t & 7;
        int n = n0 + nn;
        float4 hv = (n < NN) ? *(const float4*)&h[(size_t)n * 32 + kg * 4]
                             : make_float4(0.f, 0.f, 0.f, 0.f);
        sHt[kg * 4 + 0][nn] = hv.x; sHt[kg * 4 + 1][nn] = hv.y;
        sHt[kg * 4 + 2][nn] = hv.z; sHt[kg * 4 + 3][nn] = hv.w;
    }
    {
        int k = t >> 3, j0 = (t & 7) * 16;
#pragma unroll
        for (int q = 0; q < 16; q += 4) {
            int c = c0 + j0 + q;
            float4 mv = (c < GC) ? *(const float4*)&M[(size_t)k * GC + c]
                                 : make_float4(0.f, 0.f, 0.f, 0.f);
            *(float4*)&sM[k][j0 + q] = mv;
        }
    }
    __syncthreads();
    int cg = t & 31, ng = t >> 5;
    float4 acc0 = make_float4(0.f, 0.f, 0.f, 0.f);
    float4 acc1 = acc0, acc2 = acc0, acc3 = acc0;
#pragma unroll
    for (int k = 0; k < 32; k++) {
        float4 hv = *(const float4*)&sHt[k][ng * 4];
        float4 mv = *(const float4*)&sM[k][cg * 4];
        acc0.x += hv.x * mv.x; acc0.y += hv.x * mv.y; acc0.z += hv.x * mv.z; acc0.w += hv.x * mv.w;
        acc1.x += hv.y * mv.x; acc1.y += hv.y * mv.y; acc1.z += hv.y * mv.z; acc1.w += hv.y * mv.w;
        acc2.x += hv.z * mv.x; acc2.y += hv.z * mv.y; acc2.z += hv.z * mv.z; acc2.w += hv.z * mv.w;
        acc3.x += hv.w * mv.x; acc3.y += hv.w * mv.y; acc3.z += hv.w * mv.w == 0.f ? 0.f : 0.f; // placeholder fixed below
        acc3.z += 0.f;
        acc3.w += 0.f;
    }
    // NOTE: acc3 redone correctly below to avoid typo risk — recompute cleanly
    // (see k_geng2 — this kernel is unused)
}

// clean version (used)
__global__ __launch_bounds__(256) void k_geng2(const float* __restrict__ h,
        const float* __restrict__ M, float* __restrict__ G) {
    __shared__ float sHt[32][32];
    __shared__ float sM[32][128];
    int n0 = blockIdx.x * 32;
    int c0 = blockIdx.y * 128;
    int t = threadIdx.x;
    {
        int nn = t >> 3, kg = t & 7;
        int n = n0 + nn;
        float4 hv = (n < NN) ? *(const float4*)&h[(size_t)n * 32 + kg * 4]
                             : make_float4(0.f, 0.f, 0.f, 0.f);
        sHt[kg * 4 + 0][nn] = hv.x; sHt[kg * 4 + 1][nn] = hv.y;
        sHt[kg * 4 + 2][nn] = hv.z; sHt[kg * 4 + 3][nn] = hv.w;
    }
    {
        int k = t >> 3, j0 = (t & 7) * 16;
#pragma unroll
        for (int q = 0; q < 16; q += 4) {
            int c = c0 + j0 + q;
            float4 mv = (c < GC) ? *(const float4*)&M[(size_t)k * GC + c]
                                 : make_float4(0.f, 0.f, 0.f, 0.f);
            *(float4*)&sM[k][j0 + q] = mv;
        }
    }
    __syncthreads();
    int cg = t & 31, ng = t >> 5;
    float acc[4][4];
#pragma unroll
    for (int r = 0; r < 4; r++)
#pragma unroll
        for (int j = 0; j < 4; j++) acc[r][j] = 0.f;
#pragma unroll
    for (int k = 0; k < 32; k++) {
        float4 hv = *(const float4*)&sHt[k][ng * 4];
        float4 mv = *(const float4*)&sM[k][cg * 4];
        float hr[4] = {hv.x, hv.y, hv.z, hv.w};
#pragma unroll
        for (int r = 0; r < 4; r++) {
            acc[r][0] += hr[r] * mv.x; acc[r][1] += hr[r] * mv.y;
            acc[r][2] += hr[r] * mv.z; acc[r][3] += hr[r] * mv.w;
        }
    }
    int c = c0 + cg * 4;
    if (c < GC) {
#pragma unroll
        for (int r = 0; r < 4; r++) {
            int n = n0 + ng * 4 + r;
            if (n < NN) *(float4*)&G[(size_t)n * GC + c] = *(float4*)acc[r];
        }
    }
}

// ---------------- per-depth edge msg from G: msg = K_s[i] @ G[src] + bias-col ----------------
// 8 lanes per edge, 4 outputs each; edges pre-sorted by src for G-row cache locality.

__global__ __launch_bounds__(256) void k_msg_g(const int* __restrict__ src_s,
        const int* __restrict__ dst_s, int E, const float* __restrict__ Ks,
        const float* __restrict__ G, float* __restrict__ agg) {
    __shared__ float sK[32][68];   // padded: row stride 68 floats (16B-aligned, bank-spread)
    int i0 = blockIdx.x * 32;
    int t = threadIdx.x;
    {
        int le = t >> 3, j0 = (t & 7) * 8;
        int i = i0 + le;
        float4 a = make_float4(0.f, 0.f, 0.f, 0.f), b = a;
        if (i < E) {
            a = *(const float4*)&Ks[(size_t)i * 64 + j0];
            b = *(const float4*)&Ks[(size_t)i * 64 + j0 + 4];
        }
        *(float4*)&sK[le][j0] = a;
        *(float4*)&sK[le][j0 + 4] = b;
    }
    __syncthreads();
    int le = t >> 3, q = (t & 7) * 4;
    int i = i0 + le;
    if (i >= E) return;
    int src = src_s[i], dst = dst_s[i];
    const float* Gr = G + (size_t)src * GC;
    float4 acc = *(const float4*)(Gr + 2048 + q);   // bias-fold column
#pragma unroll 8
    for (int c = 0; c < 64; c++) {
        float kc = sK[le][c];
        float4 gv = *(const float4*)(Gr + c * 32 + q);
        acc.x += kc * gv.x; acc.y += kc * gv.y; acc.z += kc * gv.z; acc.w += kc * gv.w;
    }
    float* ap = agg + (size_t)dst * WID + q;
    unsafeAtomicAdd(ap + 0, acc.x);
    unsafeAtomicAdd(ap + 1, acc.y);
    unsafeAtomicAdd(ap + 2, acc.z);
    unsafeAtomicAdd(ap + 3, acc.w);
}

// ---------------- fallback (lean ws): fused msg from K and w3 ----------------

__global__ __launch_bounds__(256) void k_msg_fused(const int* __restrict__ ei, int E,
        const float* __restrict__ h, const float* __restrict__ Kf,
        const float* __restrict__ w3, const float* __restrict__ b3,
        float* __restrict__ agg) {
    __shared__ float sw3[8 * 1024];
    int lane = threadIdx.x & 63;
    int wid  = threadIdx.x >> 6;
    int sub  = lane >> 5;
    int o    = lane & 31;
    int e = blockIdx.x * 8 + wid * 2 + sub;
    bool valid = (e < E);
    int ec = valid ? e : 0;
    int src = ei[ec];
    int dst = ei[E + ec];
    float hs[32];
#pragma unroll
    for (int i = 0; i < 32; i++) hs[i] = h[(size_t)src * WID + i];
    float msg = 0.0f;
#pragma unroll
    for (int i = 0; i < 32; i++) msg += hs[i] * b3[i * 32 + o];
    for (int cc = 0; cc < 64; cc += 8) {
        __syncthreads();
        for (int i = threadIdx.x; i < 8 * 1024; i += 256) sw3[i] = w3[(size_t)cc * 1024 + i];
        __syncthreads();
#pragma unroll
        for (int c = 0; c < 8; c++) {
            float s = 0.0f;
#pragma unroll
            for (int i = 0; i < 32; i++) s += hs[i] * sw3[c * 1024 + i * 32 + o];
            msg += Kf[(size_t)ec * KW + cc + c] * s;
        }
    }
    if (valid) unsafeAtomicAdd(&agg[(size_t)dst * WID + o], msg);
}

// ---------------- node update + output ----------------

__global__ __launch_bounds__(256) void k_node(const float* __restrict__ hin,
        float* __restrict__ hout,
        const float* __restrict__ agg1, const float* __restrict__ aggb,
        const float* __restrict__ inv1, const float* __restrict__ invb,
        const float* __restrict__ h0, const float* __restrict__ rs,
        const float* __restrict__ bs) {
    __shared__ float sR[1024];
    __shared__ float sB[32];
    for (int i = threadIdx.x; i < 1024; i += 256) sR[i] = rs[i];
    if (threadIdx.x < 32) sB[threadIdx.x] = bs[threadIdx.x];
    __syncthreads();
    int t = blockIdx.x * 256 + threadIdx.x;
    if (t >= NN * WID) return;
    int n = t >> 5, j = t & 31;
    float s = agg1[t] * inv1[n] + aggb[t] * invb[n] + sB[j];
    const float* hr = hin + (size_t)n * WID;
#pragma unroll
    for (int i = 0; i < 32; i++) s += hr[i] * sR[i * 32 + j];
    hout[t] = fmaxf(s, 0.0f) + h0[t];
}

__global__ void k_fc2(const float* __restrict__ h, const float* __restrict__ w,
                      const float* __restrict__ b, float* __restrict__ out) {
    int n = blockIdx.x * blockDim.x + threadIdx.x;
    if (n >= NN) return;
    const float4* hv = (const float4*)(h + (size_t)n * WID);
    const float4* wv = (const float4*)w;
    float s = b[0];
#pragma unroll
    for (int q = 0; q < 8; q++) {
        float4 a = hv[q], c = wv[q];
        s += a.x * c.x + a.y * c.y + a.z * c.z + a.w * c.w;
    }
    out[n] = s;
}

// ---------------- launch ----------------

extern "C" void kernel_launch(void* const* d_in, const int* in_sizes, int n_in,
                              void* d_out, int out_size, void* d_ws, size_t ws_size,
                              hipStream_t stream) {
    const float* x    = (const float*)d_in[0];
    const int*   ei   = (const int*)d_in[1];
    const float* ea   = (const float*)d_in[2];
    const int*   eib  = (const int*)d_in[3];
    const float* eab  = (const float*)d_in[4];
    const float* fc1w = (const float*)d_in[5];
    const float* fc1b = (const float*)d_in[6];
    const float* fc2w = (const float*)d_in[7];
    const float* fc2b = (const float*)d_in[8];
    const float* k1w1 = (const float*)d_in[9];
    const float* k1b1 = (const float*)d_in[10];
    const float* k1w2 = (const float*)d_in[11];
    const float* k1b2 = (const float*)d_in[12];
    const float* k1w3 = (const float*)d_in[13];
    const float* k1b3 = (const float*)d_in[14];
    const float* root1= (const float*)d_in[15];
    const float* bias1= (const float*)d_in[16];
    const float* k2w1 = (const float*)d_in[17];
    const float* k2b1 = (const float*)d_in[18];
    const float* k2w2 = (const float*)d_in[19];
    const float* k2b2 = (const float*)d_in[20];
    const float* k2w3 = (const float*)d_in[21];
    const float* k2b3 = (const float*)d_in[22];
    const float* root2= (const float*)d_in[23];
    const float* bias2= (const float*)d_in[24];

    float* p = (float*)d_ws;
    auto alloc = [&](size_t nflt) { float* r = p; p += nflt; return r; };
    float* K1   = alloc((size_t)EM * KW);     // sorted order in full path
    float* Kb   = alloc((size_t)EBN * KW);
    float* h0   = alloc((size_t)NN * WID);
    float* hA   = alloc((size_t)NN * WID);
    float* hB   = alloc((size_t)NN * WID);
    float* agg1 = alloc((size_t)NN * WID);
    float* aggb = alloc((size_t)NN * WID);
    float* inv1 = alloc(NN);
    float* invb = alloc(NN);
    float* rs   = alloc(1024);
    float* bs   = alloc(32);
    int*   cnt1 = (int*)alloc(NN);   // dst counts (main)
    int*   cntb = (int*)alloc(NN);   // dst counts (boundary)
    int*   cs1  = (int*)alloc(NN);   // src counts (main)
    int*   csb  = (int*)alloc(NN);   // src counts (boundary)
    int*   cur1 = (int*)alloc(NN);
    int*   curb = (int*)alloc(NN);
    int*   perm1= (int*)alloc(EM);
    int*   permb= (int*)alloc(EBN);
    int*   srcs1= (int*)alloc(EM);
    int*   dsts1= (int*)alloc(EM);
    int*   srcsb= (int*)alloc(EBN);
    int*   dstsb= (int*)alloc(EBN);
    float* M1   = alloc(32 * GC);
    float* M2   = alloc(32 * GC);
    float* G1   = alloc((size_t)NN * GC);
    float* G2   = alloc((size_t)NN * GC);
    size_t full_bytes = (size_t)((char*)p - (char*)d_ws);
    bool full = (ws_size >= full_bytes);

    hipMemsetAsync(cnt1, 0, NN * sizeof(int), stream);
    hipMemsetAsync(cntb, 0, NN * sizeof(int), stream);
    k_prep<<<1, 1024, 0, stream>>>(root1, bias1, root2, bias2, rs, bs);
    k_h0<<<(NN * WID + 255) / 256, 256, 0, stream>>>(x, fc1w, fc1b, h0, hA);
    k_count<<<(EM + 255) / 256, 256, 0, stream>>>(ei + EM, EM, cnt1);
    k_count<<<(EBN + 255) / 256, 256, 0, stream>>>(eib + EBN, EBN, cntb);
    k_inv<<<(NN + 255) / 256, 256, 0, stream>>>(cnt1, inv1, NN);
    k_inv<<<(NN + 255) / 256, 256, 0, stream>>>(cntb, invb, NN);

    if (full) {
        hipMemsetAsync(cs1, 0, NN * sizeof(int), stream);
        hipMemsetAsync(csb, 0, NN * sizeof(int), stream);
        k_count<<<(EM + 255) / 256, 256, 0, stream>>>(ei, EM, cs1);
        k_count<<<(EBN + 255) / 256, 256, 0, stream>>>(eib, EBN, csb);
        k_scan<<<1, 1024, 0, stream>>>(cs1, cur1, NN);
        k_scan<<<1, 1024, 0, stream>>>(csb, curb, NN);
        k_scatter<<<(EM + 255) / 256, 256, 0, stream>>>(ei, EM, cur1, perm1);
        k_scatter<<<(EBN + 255) / 256, 256, 0, stream>>>(eib, EBN, curb, permb);
        k_permidx<<<(EM + 255) / 256, 256, 0, stream>>>(ei, EM, perm1, srcs1, dsts1);
        k_permidx<<<(EBN + 255) / 256, 256, 0, stream>>>(eib, EBN, permb, srcsb, dstsb);
        k_mlp<<<(EM + 255) / 256, 256, 0, stream>>>(ea, EM, k1w1, k1b1, k1w2, k1b2, perm1, K1);
        k_mlp<<<(EBN + 255) / 256, 256, 0, stream>>>(eab, EBN, k2w1, k2b1, k2w2, k2b2, permb, Kb);
        k_permM<<<(32 * GC + 255) / 256, 256, 0, stream>>>(k1w3, k1b3, M1);
        k_permM<<<(32 * GC + 255) / 256, 256, 0, stream>>>(k2w3, k2b3, M2);
    } else {
        k_mlp<<<(EM + 255) / 256, 256, 0, stream>>>(ea, EM, k1w1, k1b1, k1w2, k1b2, nullptr, K1);
        k_mlp<<<(EBN + 255) / 256, 256, 0, stream>>>(eab, EBN, k2w1, k2b1, k2w2, k2b2, nullptr, Kb);
    }

    const float* hin = hA;
    float* hout = hB;
    dim3 ggrid((NN + 31) / 32, (GC + 127) / 128);
    for (int d = 0; d < NDEPTH; d++) {
        hipMemsetAsync(agg1, 0, (size_t)NN * WID * sizeof(float), stream);
        hipMemsetAsync(aggb, 0, (size_t)NN * WID * sizeof(float), stream);
        if (full) {
            k_geng2<<<ggrid, 256, 0, stream>>>(hin, M1, G1);
            k_geng2<<<ggrid, 256, 0, stream>>>(hin, M2, G2);
            k_msg_g<<<(EM + 31) / 32, 256, 0, stream>>>(srcs1, dsts1, EM, K1, G1, agg1);
            k_msg_g<<<(EBN + 31) / 32, 256, 0, stream>>>(srcsb, dstsb, EBN, Kb, G2, aggb);
        } else {
            k_msg_fused<<<(EM + 7) / 8, 256, 0, stream>>>(ei, EM, hin, K1, k1w3, k1b3, agg1);
            k_msg_fused<<<(EBN + 7) / 8, 256, 0, stream>>>(eib, EBN, hin, Kb, k2w3, k2b3, aggb);
        }
        k_node<<<(NN * WID + 255) / 256, 256, 0, stream>>>(hin, hout, agg1, aggb,
                                                           inv1, invb, h0, rs, bs);
        float* tmp = (float*)hin; hin = hout; hout = tmp;
    }
    k_fc2<<<(NN + 255) / 256, 256, 0, stream>>>(hin, fc2w, fc2b, (float*)d_out);
}

// Round 3
// 1732.160 us; speedup vs baseline: 1.5184x; 1.5155x over previous
//
#include <hip/hip_runtime.h>
#include <cstdint>
#include <cstddef>

#define NN    20000
#define EM    100000
#define EBN   20000
#define WID   32
#define KW    64
#define KIN   6
#define NDEPTH 4
#define GC    2080   // 64*32 kernel cols + 32 bias cols

// ---------------- small setup kernels ----------------

__global__ void k_prep(const float* __restrict__ r1, const float* __restrict__ b1,
                       const float* __restrict__ r2, const float* __restrict__ b2,
                       float* __restrict__ rs, float* __restrict__ bs) {
    int i = threadIdx.x;
    if (i < 1024) rs[i] = r1[i] + r2[i];
    if (i < 32)   bs[i] = b1[i] + b2[i];
}

__global__ void k_h0(const float* __restrict__ x, const float* __restrict__ fc1w,
                     const float* __restrict__ fc1b, float* __restrict__ h0,
                     float* __restrict__ h) {
    int t = blockIdx.x * blockDim.x + threadIdx.x;
    if (t >= NN * WID) return;
    int node = t >> 5, j = t & 31;
    float v = x[node] * fc1w[j] + fc1b[j];
    h0[t] = v; h[t] = v;
}

__global__ void k_count(const int* __restrict__ idx, int E, int* __restrict__ cnt) {
    int e = blockIdx.x * blockDim.x + threadIdx.x;
    if (e < E) atomicAdd(&cnt[idx[e]], 1);
}

__global__ void k_inv(const int* __restrict__ cnt, float* __restrict__ inv, int n) {
    int i = blockIdx.x * blockDim.x + threadIdx.x;
    if (i < n) {
        int c = cnt[i]; if (c < 1) c = 1;
        inv[i] = 1.0f / (float)c;
    }
}

// exclusive prefix sum of cnt[0..n) -> cur[0..n), single block 1024 threads
__global__ __launch_bounds__(1024) void k_scan(const int* __restrict__ cnt,
                                               int* __restrict__ cur, int n) {
    __shared__ int part[1024];
    int t = threadIdx.x;
    int per = (n + 1023) / 1024;
    int base = t * per;
    int s = 0;
    for (int i = 0; i < per; i++) { int idx = base + i; if (idx < n) s += cnt[idx]; }
    part[t] = s;
    __syncthreads();
    for (int off = 1; off < 1024; off <<= 1) {
        int v = (t >= off) ? part[t - off] : 0;
        __syncthreads();
        part[t] += v;
        __syncthreads();
    }
    int run = (t > 0) ? part[t - 1] : 0;
    for (int i = 0; i < per; i++) {
        int idx = base + i;
        if (idx < n) { cur[idx] = run; run += cnt[idx]; }
    }
}

__global__ void k_scatter(const int* __restrict__ src, int E,
                          int* __restrict__ cur, int* __restrict__ perm) {
    int e = blockIdx.x * blockDim.x + threadIdx.x;
    if (e < E) { int p = atomicAdd(&cur[src[e]], 1); perm[p] = e; }
}

__global__ void k_permidx(const int* __restrict__ ei, int E,
                          const int* __restrict__ perm,
                          int* __restrict__ src_s, int* __restrict__ dst_s) {
    int i = blockIdx.x * blockDim.x + threadIdx.x;
    if (i >= E) return;
    int e = perm[i];
    src_s[i] = ei[e];
    dst_s[i] = ei[E + e];
}

// M[i][c*32+o] = w3[c][i*32+o] (c<64); M[i][2048+o] = b3[i*32+o]
__global__ void k_permM(const float* __restrict__ w3, const float* __restrict__ b3,
                        float* __restrict__ M) {
    int t = blockIdx.x * blockDim.x + threadIdx.x;
    if (t >= 32 * GC) return;
    int i = t / GC, c = t % GC;
    if (c < 2048) {
        int cc = c >> 5, o = c & 31;
        M[t] = w3[cc * 1024 + i * 32 + o];
    } else {
        M[t] = b3[i * 32 + (c - 2048)];
    }
}

// ---------------- edge MLP: ea(E x 6) -> K(E x 64), optionally permuted order ----------------

__global__ __launch_bounds__(256) void k_mlp(const float* __restrict__ ea, int E,
        const float* __restrict__ w1, const float* __restrict__ b1,
        const float* __restrict__ w2, const float* __restrict__ b2,
        const int* __restrict__ perm, float* __restrict__ K) {
    __shared__ float sw1[KIN * KW];
    __shared__ float sw2[KW * KW];
    __shared__ float sb1[KW];
    __shared__ float sb2[KW];
    for (int i = threadIdx.x; i < KIN * KW; i += 256) sw1[i] = w1[i];
    for (int i = threadIdx.x; i < KW * KW; i += 256)  sw2[i] = w2[i];
    if (threadIdx.x < KW) { sb1[threadIdx.x] = b1[threadIdx.x]; sb2[threadIdx.x] = b2[threadIdx.x]; }
    __syncthreads();
    int e = blockIdx.x * 256 + threadIdx.x;
    if (e >= E) return;
    int eo = perm ? perm[e] : e;
    float a[KIN];
#pragma unroll
    for (int i = 0; i < KIN; i++) a[i] = ea[(size_t)eo * KIN + i];
    float t[KW];
#pragma unroll 8
    for (int j = 0; j < KW; j++) {
        float s = sb1[j];
#pragma unroll
        for (int i = 0; i < KIN; i++) s += a[i] * sw1[i * KW + j];
        t[j] = fmaxf(s, 0.0f);
    }
#pragma unroll 4
    for (int j = 0; j < KW; j++) {
        float s = sb2[j];
#pragma unroll 16
        for (int c = 0; c < KW; c++) s += t[c] * sw2[c * KW + j];
        K[(size_t)e * KW + j] = fmaxf(s, 0.0f);
    }
}

// ---------------- chunked GEMM: G[(n-n0)] = H[n] @ M  for n in [n0, nend) ----------------
// block 256: tile 32 nodes x 128 cols; thread = 4 nodes x 4 cols

__global__ __launch_bounds__(256) void k_geng_chunk(const float* __restrict__ h,
        const float* __restrict__ M, float* __restrict__ G, int n0, int nend) {
    __shared__ float sHt[32][32];
    __shared__ float sM[32][128];
    int nb = n0 + blockIdx.x * 32;
    int c0 = blockIdx.y * 128;
    int t = threadIdx.x;
    {
        int nn = t >> 3, kg = t & 7;
        int n = nb + nn;
        float4 hv = (n < nend) ? *(const float4*)&h[(size_t)n * 32 + kg * 4]
                               : make_float4(0.f, 0.f, 0.f, 0.f);
        sHt[kg * 4 + 0][nn] = hv.x; sHt[kg * 4 + 1][nn] = hv.y;
        sHt[kg * 4 + 2][nn] = hv.z; sHt[kg * 4 + 3][nn] = hv.w;
    }
    {
        int k = t >> 3, j0 = (t & 7) * 16;
#pragma unroll
        for (int q = 0; q < 16; q += 4) {
            int c = c0 + j0 + q;
            float4 mv = (c < GC) ? *(const float4*)&M[(size_t)k * GC + c]
                                 : make_float4(0.f, 0.f, 0.f, 0.f);
            *(float4*)&sM[k][j0 + q] = mv;
        }
    }
    __syncthreads();
    int cg = t & 31, ng = t >> 5;
    float acc[4][4];
#pragma unroll
    for (int r = 0; r < 4; r++)
#pragma unroll
        for (int j = 0; j < 4; j++) acc[r][j] = 0.f;
#pragma unroll
    for (int k = 0; k < 32; k++) {
        float4 hv = *(const float4*)&sHt[k][ng * 4];
        float4 mv = *(const float4*)&sM[k][cg * 4];
        float hr[4] = {hv.x, hv.y, hv.z, hv.w};
#pragma unroll
        for (int r = 0; r < 4; r++) {
            acc[r][0] += hr[r] * mv.x; acc[r][1] += hr[r] * mv.y;
            acc[r][2] += hr[r] * mv.z; acc[r][3] += hr[r] * mv.w;
        }
    }
    int c = c0 + cg * 4;
    if (c < GC) {
#pragma unroll
        for (int r = 0; r < 4; r++) {
            int n = nb + ng * 4 + r;
            if (n < nend) *(float4*)&G[(size_t)(n - n0) * GC + c] = *(float4*)acc[r];
        }
    }
}

// ---------------- chunked edge msg: msg = K_s[i] @ G[src-n0] + bias-col ----------------
// edges sorted by src; 8 lanes/edge, 4 outputs each. XCD-bijective block swizzle.

__global__ __launch_bounds__(256) void k_msg_chunk(const int* __restrict__ src_s,
        const int* __restrict__ dst_s, int E, const float* __restrict__ Ks,
        const float* __restrict__ G, float* __restrict__ agg, int n0, int nend) {
    // bijective XCD swizzle: hardware XCD (= orig%8 heuristic) gets contiguous work
    int nwg = gridDim.x;
    int orig = blockIdx.x;
    int qq = nwg >> 3, rr = nwg & 7;
    int xc = orig & 7, oo = orig >> 3;
    int bid = (xc < rr ? xc * (qq + 1) : rr * (qq + 1) + (xc - rr) * qq) + oo;
    int i0 = bid * 32;
    if (i0 >= E) return;
    int ilast = min(i0 + 31, E - 1);
    if (src_s[ilast] < n0 || src_s[i0] >= nend) return;   // uniform: chunk range test
    __shared__ float sK[32][68];
    int t = threadIdx.x;
    {
        int le = t >> 3, j0 = (t & 7) * 8;
        int i = i0 + le;
        float4 a = make_float4(0.f, 0.f, 0.f, 0.f), b = a;
        if (i < E) {
            a = *(const float4*)&Ks[(size_t)i * 64 + j0];
            b = *(const float4*)&Ks[(size_t)i * 64 + j0 + 4];
        }
        *(float4*)&sK[le][j0] = a;
        *(float4*)&sK[le][j0 + 4] = b;
    }
    __syncthreads();
    int le = t >> 3, q = (t & 7) * 4;
    int i = i0 + le;
    if (i >= E) return;
    int src = src_s[i];
    if (src < n0 || src >= nend) return;
    int dst = dst_s[i];
    const float* Gr = G + (size_t)(src - n0) * GC;
    float4 acc = *(const float4*)(Gr + 2048 + q);   // bias-fold column
#pragma unroll 8
    for (int c = 0; c < 64; c++) {
        float kc = sK[le][c];
        float4 gv = *(const float4*)(Gr + c * 32 + q);
        acc.x += kc * gv.x; acc.y += kc * gv.y; acc.z += kc * gv.z; acc.w += kc * gv.w;
    }
    float* ap = agg + (size_t)dst * WID + q;
    unsafeAtomicAdd(ap + 0, acc.x);
    unsafeAtomicAdd(ap + 1, acc.y);
    unsafeAtomicAdd(ap + 2, acc.z);
    unsafeAtomicAdd(ap + 3, acc.w);
}

// ---------------- fallback (lean ws): fused msg from K and w3 ----------------

__global__ __launch_bounds__(256) void k_msg_fused(const int* __restrict__ ei, int E,
        const float* __restrict__ h, const float* __restrict__ Kf,
        const float* __restrict__ w3, const float* __restrict__ b3,
        float* __restrict__ agg) {
    __shared__ float sw3[8 * 1024];
    int lane = threadIdx.x & 63;
    int wid  = threadIdx.x >> 6;
    int sub  = lane >> 5;
    int o    = lane & 31;
    int e = blockIdx.x * 8 + wid * 2 + sub;
    bool valid = (e < E);
    int ec = valid ? e : 0;
    int src = ei[ec];
    int dst = ei[E + ec];
    float hs[32];
#pragma unroll
    for (int i = 0; i < 32; i++) hs[i] = h[(size_t)src * WID + i];
    float msg = 0.0f;
#pragma unroll
    for (int i = 0; i < 32; i++) msg += hs[i] * b3[i * 32 + o];
    for (int cc = 0; cc < 64; cc += 8) {
        __syncthreads();
        for (int i = threadIdx.x; i < 8 * 1024; i += 256) sw3[i] = w3[(size_t)cc * 1024 + i];
        __syncthreads();
#pragma unroll
        for (int c = 0; c < 8; c++) {
            float s = 0.0f;
#pragma unroll
            for (int i = 0; i < 32; i++) s += hs[i] * sw3[c * 1024 + i * 32 + o];
            msg += Kf[(size_t)ec * KW + cc + c] * s;
        }
    }
    if (valid) unsafeAtomicAdd(&agg[(size_t)dst * WID + o], msg);
}

// ---------------- node update + output ----------------

__global__ __launch_bounds__(256) void k_node(const float* __restrict__ hin,
        float* __restrict__ hout,
        const float* __restrict__ agg1, const float* __restrict__ aggb,
        const float* __restrict__ inv1, const float* __restrict__ invb,
        const float* __restrict__ h0, const float* __restrict__ rs,
        const float* __restrict__ bs) {
    __shared__ float sR[1024];
    __shared__ float sB[32];
    for (int i = threadIdx.x; i < 1024; i += 256) sR[i] = rs[i];
    if (threadIdx.x < 32) sB[threadIdx.x] = bs[threadIdx.x];
    __syncthreads();
    int t = blockIdx.x * 256 + threadIdx.x;
    if (t >= NN * WID) return;
    int n = t >> 5, j = t & 31;
    float s = agg1[t] * inv1[n] + aggb[t] * invb[n] + sB[j];
    const float* hr = hin + (size_t)n * WID;
#pragma unroll
    for (int i = 0; i < 32; i++) s += hr[i] * sR[i * 32 + j];
    hout[t] = fmaxf(s, 0.0f) + h0[t];
}

__global__ void k_fc2(const float* __restrict__ h, const float* __restrict__ w,
                      const float* __restrict__ b, float* __restrict__ out) {
    int n = blockIdx.x * blockDim.x + threadIdx.x;
    if (n >= NN) return;
    const float4* hv = (const float4*)(h + (size_t)n * WID);
    const float4* wv = (const float4*)w;
    float s = b[0];
#pragma unroll
    for (int q = 0; q < 8; q++) {
        float4 a = hv[q], c = wv[q];
        s += a.x * c.x + a.y * c.y + a.z * c.z + a.w * c.w;
    }
    out[n] = s;
}

// ---------------- launch ----------------

extern "C" void kernel_launch(void* const* d_in, const int* in_sizes, int n_in,
                              void* d_out, int out_size, void* d_ws, size_t ws_size,
                              hipStream_t stream) {
    const float* x    = (const float*)d_in[0];
    const int*   ei   = (const int*)d_in[1];
    const float* ea   = (const float*)d_in[2];
    const int*   eib  = (const int*)d_in[3];
    const float* eab  = (const float*)d_in[4];
    const float* fc1w = (const float*)d_in[5];
    const float* fc1b = (const float*)d_in[6];
    const float* fc2w = (const float*)d_in[7];
    const float* fc2b = (const float*)d_in[8];
    const float* k1w1 = (const float*)d_in[9];
    const float* k1b1 = (const float*)d_in[10];
    const float* k1w2 = (const float*)d_in[11];
    const float* k1b2 = (const float*)d_in[12];
    const float* k1w3 = (const float*)d_in[13];
    const float* k1b3 = (const float*)d_in[14];
    const float* root1= (const float*)d_in[15];
    const float* bias1= (const float*)d_in[16];
    const float* k2w1 = (const float*)d_in[17];
    const float* k2b1 = (const float*)d_in[18];
    const float* k2w2 = (const float*)d_in[19];
    const float* k2b2 = (const float*)d_in[20];
    const float* k2w3 = (const float*)d_in[21];
    const float* k2b3 = (const float*)d_in[22];
    const float* root2= (const float*)d_in[23];
    const float* bias2= (const float*)d_in[24];

    float* p = (float*)d_ws;
    auto alloc = [&](size_t nflt) { float* r = p; p += nflt; return r; };
    float* K1   = alloc((size_t)EM * KW);     // sorted order in full path
    float* Kb   = alloc((size_t)EBN * KW);
    float* h0   = alloc((size_t)NN * WID);
    float* hA   = alloc((size_t)NN * WID);
    float* hB   = alloc((size_t)NN * WID);
    float* agg1 = alloc((size_t)NN * WID);
    float* aggb = alloc((size_t)NN * WID);
    float* inv1 = alloc(NN);
    float* invb = alloc(NN);
    float* rs   = alloc(1024);
    float* bs   = alloc(32);
    int*   cnt1 = (int*)alloc(NN);
    int*   cntb = (int*)alloc(NN);
    int*   cs1  = (int*)alloc(NN);
    int*   csb  = (int*)alloc(NN);
    int*   cur1 = (int*)alloc(NN);
    int*   curb = (int*)alloc(NN);
    int*   perm1= (int*)alloc(EM);
    int*   permb= (int*)alloc(EBN);
    int*   srcs1= (int*)alloc(EM);
    int*   dsts1= (int*)alloc(EM);
    int*   srcsb= (int*)alloc(EBN);
    int*   dstsb= (int*)alloc(EBN);
    float* M1   = alloc(32 * GC);
    float* M2   = alloc(32 * GC);
    float* Gbuf = p;   // remaining space: shared G chunk buffer

    size_t base_bytes = (size_t)((char*)p - (char*)d_ws);
    size_t rem = (ws_size > base_bytes) ? ws_size - base_bytes : 0;
    long long cn = (long long)(rem / ((size_t)GC * sizeof(float)));
    if (cn > NN) cn = NN;
    cn &= ~31LL;                       // multiple of 32
    bool full = (cn >= 512);
    int chunk_nodes = (int)cn;

    hipMemsetAsync(cnt1, 0, NN * sizeof(int), stream);
    hipMemsetAsync(cntb, 0, NN * sizeof(int), stream);
    k_prep<<<1, 1024, 0, stream>>>(root1, bias1, root2, bias2, rs, bs);
    k_h0<<<(NN * WID + 255) / 256, 256, 0, stream>>>(x, fc1w, fc1b, h0, hA);
    k_count<<<(EM + 255) / 256, 256, 0, stream>>>(ei + EM, EM, cnt1);
    k_count<<<(EBN + 255) / 256, 256, 0, stream>>>(eib + EBN, EBN, cntb);
    k_inv<<<(NN + 255) / 256, 256, 0, stream>>>(cnt1, inv1, NN);
    k_inv<<<(NN + 255) / 256, 256, 0, stream>>>(cntb, invb, NN);

    if (full) {
        hipMemsetAsync(cs1, 0, NN * sizeof(int), stream);
        hipMemsetAsync(csb, 0, NN * sizeof(int), stream);
        k_count<<<(EM + 255) / 256, 256, 0, stream>>>(ei, EM, cs1);
        k_count<<<(EBN + 255) / 256, 256, 0, stream>>>(eib, EBN, csb);
        k_scan<<<1, 1024, 0, stream>>>(cs1, cur1, NN);
        k_scan<<<1, 1024, 0, stream>>>(csb, curb, NN);
        k_scatter<<<(EM + 255) / 256, 256, 0, stream>>>(ei, EM, cur1, perm1);
        k_scatter<<<(EBN + 255) / 256, 256, 0, stream>>>(eib, EBN, curb, permb);
        k_permidx<<<(EM + 255) / 256, 256, 0, stream>>>(ei, EM, perm1, srcs1, dsts1);
        k_permidx<<<(EBN + 255) / 256, 256, 0, stream>>>(eib, EBN, permb, srcsb, dstsb);
        k_mlp<<<(EM + 255) / 256, 256, 0, stream>>>(ea, EM, k1w1, k1b1, k1w2, k1b2, perm1, K1);
        k_mlp<<<(EBN + 255) / 256, 256, 0, stream>>>(eab, EBN, k2w1, k2b1, k2w2, k2b2, permb, Kb);
        k_permM<<<(32 * GC + 255) / 256, 256, 0, stream>>>(k1w3, k1b3, M1);
        k_permM<<<(32 * GC + 255) / 256, 256, 0, stream>>>(k2w3, k2b3, M2);
    } else {
        k_mlp<<<(EM + 255) / 256, 256, 0, stream>>>(ea, EM, k1w1, k1b1, k1w2, k1b2, nullptr, K1);
        k_mlp<<<(EBN + 255) / 256, 256, 0, stream>>>(eab, EBN, k2w1, k2b1, k2w2, k2b2, nullptr, Kb);
    }

    const float* hin = hA;
    float* hout = hB;
    int NC = full ? (NN + chunk_nodes - 1) / chunk_nodes : 0;
    for (int d = 0; d < NDEPTH; d++) {
        hipMemsetAsync(agg1, 0, (size_t)NN * WID * sizeof(float), stream);
        hipMemsetAsync(aggb, 0, (size_t)NN * WID * sizeof(float), stream);
        if (full) {
            for (int c = 0; c < NC; c++) {
                int n0 = c * chunk_nodes;
                int nend = min(n0 + chunk_nodes, NN);
                dim3 gg(((nend - n0) + 31) / 32, (GC + 127) / 128);
                k_geng_chunk<<<gg, 256, 0, stream>>>(hin, M1, Gbuf, n0, nend);
                k_msg_chunk<<<(EM + 31) / 32, 256, 0, stream>>>(srcs1, dsts1, EM, K1,
                                                                Gbuf, agg1, n0, nend);
            }
            for (int c = 0; c < NC; c++) {
                int n0 = c * chunk_nodes;
                int nend = min(n0 + chunk_nodes, NN);
                dim3 gg(((nend - n0) + 31) / 32, (GC + 127) / 128);
                k_geng_chunk<<<gg, 256, 0, stream>>>(hin, M2, Gbuf, n0, nend);
                k_msg_chunk<<<(EBN + 31) / 32, 256, 0, stream>>>(srcsb, dstsb, EBN, Kb,
                                                                 Gbuf, aggb, n0, nend);
            }
        } else {
            k_msg_fused<<<(EM + 7) / 8, 256, 0, stream>>>(ei, EM, hin, K1, k1w3, k1b3, agg1);
            k_msg_fused<<<(EBN + 7) / 8, 256, 0, stream>>>(eib, EBN, hin, Kb, k2w3, k2b3, aggb);
        }
        k_node<<<(NN * WID + 255) / 256, 256, 0, stream>>>(hin, hout, agg1, aggb,
                                                           inv1, invb, h0, rs, bs);
        float* tmp = (float*)hin; hin = hout; hout = tmp;
    }
    k_fc2<<<(NN + 255) / 256, 256, 0, stream>>>(hin, fc2w, fc2b, (float*)d_out);
}

// Round 4
// 848.974 us; speedup vs baseline: 3.0981x; 2.0403x over previous
//
#include <hip/hip_runtime.h>
#include <cstdint>
#include <cstddef>

#define NN    20000
#define EM    100000
#define EBN   20000
#define WID   32
#define KW    64
#define KIN   6
#define NDEPTH 4
#define GC    2080   // 64*32 kernel cols + 32 bias cols
#define NB    8      // nodes per fuse-block
#define GROW  2084   // padded LDS row (2084 % 32 == 4 -> rows hit distinct bank offsets)

// ---------------- small setup kernels ----------------

__global__ void k_prep(const float* __restrict__ r1, const float* __restrict__ b1,
                       const float* __restrict__ r2, const float* __restrict__ b2,
                       float* __restrict__ rs, float* __restrict__ bs) {
    int i = threadIdx.x;
    if (i < 1024) rs[i] = r1[i] + r2[i];
    if (i < 32)   bs[i] = b1[i] + b2[i];
}

__global__ void k_h0(const float* __restrict__ x, const float* __restrict__ fc1w,
                     const float* __restrict__ fc1b, float* __restrict__ h0,
                     float* __restrict__ h) {
    int t = blockIdx.x * blockDim.x + threadIdx.x;
    if (t >= NN * WID) return;
    int node = t >> 5, j = t & 31;
    float v = x[node] * fc1w[j] + fc1b[j];
    h0[t] = v; h[t] = v;
}

__global__ void k_count(const int* __restrict__ idx, int E, int* __restrict__ cnt) {
    int e = blockIdx.x * blockDim.x + threadIdx.x;
    if (e < E) atomicAdd(&cnt[idx[e]], 1);
}

__global__ void k_inv(const int* __restrict__ cnt, float* __restrict__ inv, int n) {
    int i = blockIdx.x * blockDim.x + threadIdx.x;
    if (i < n) {
        int c = cnt[i]; if (c < 1) c = 1;
        inv[i] = 1.0f / (float)c;
    }
}

// exclusive scan of cnt -> cur (scatter cursor) and off (persistent CSR, off[n]=E)
__global__ __launch_bounds__(1024) void k_scan(const int* __restrict__ cnt,
                                               int* __restrict__ cur,
                                               int* __restrict__ off, int n) {
    __shared__ int part[1024];
    int t = threadIdx.x;
    int per = (n + 1023) / 1024;
    int base = t * per;
    int s = 0;
    for (int i = 0; i < per; i++) { int idx = base + i; if (idx < n) s += cnt[idx]; }
    part[t] = s;
    __syncthreads();
    for (int offd = 1; offd < 1024; offd <<= 1) {
        int v = (t >= offd) ? part[t - offd] : 0;
        __syncthreads();
        part[t] += v;
        __syncthreads();
    }
    int run = (t > 0) ? part[t - 1] : 0;
    for (int i = 0; i < per; i++) {
        int idx = base + i;
        if (idx < n) { cur[idx] = run; off[idx] = run; run += cnt[idx]; }
    }
    if (t == 1023) off[n] = part[1023];
}

__global__ void k_scatter(const int* __restrict__ src, int E,
                          int* __restrict__ cur, int* __restrict__ perm) {
    int e = blockIdx.x * blockDim.x + threadIdx.x;
    if (e < E) { int p = atomicAdd(&cur[src[e]], 1); perm[p] = e; }
}

__global__ void k_permidx(const int* __restrict__ ei, int E,
                          const int* __restrict__ perm,
                          int* __restrict__ src_s, int* __restrict__ dst_s) {
    int i = blockIdx.x * blockDim.x + threadIdx.x;
    if (i >= E) return;
    int e = perm[i];
    src_s[i] = ei[e];
    dst_s[i] = ei[E + e];
}

// M[i][c*32+o] = w3[c][i*32+o] (c<64); M[i][2048+o] = b3[i*32+o]
__global__ void k_permM(const float* __restrict__ w3, const float* __restrict__ b3,
                        float* __restrict__ M) {
    int t = blockIdx.x * blockDim.x + threadIdx.x;
    if (t >= 32 * GC) return;
    int i = t / GC, c = t % GC;
    if (c < 2048) {
        int cc = c >> 5, o = c & 31;
        M[t] = w3[cc * 1024 + i * 32 + o];
    } else {
        M[t] = b3[i * 32 + (c - 2048)];
    }
}

// ---------------- edge MLP: ea(E x 6) -> K(E x 64), permuted order ----------------
// ALL loops touching local arrays fully unrolled (runtime-indexed locals -> scratch).

__global__ __launch_bounds__(256) void k_mlp(const float* __restrict__ ea, int E,
        const float* __restrict__ w1, const float* __restrict__ b1,
        const float* __restrict__ w2, const float* __restrict__ b2,
        const int* __restrict__ perm, float* __restrict__ K) {
    __shared__ float sw1[KIN * KW];
    __shared__ float sw2[KW * KW];
    __shared__ float sb1[KW];
    __shared__ float sb2[KW];
    for (int i = threadIdx.x; i < KIN * KW; i += 256) sw1[i] = w1[i];
    for (int i = threadIdx.x; i < KW * KW; i += 256)  sw2[i] = w2[i];
    if (threadIdx.x < KW) { sb1[threadIdx.x] = b1[threadIdx.x]; sb2[threadIdx.x] = b2[threadIdx.x]; }
    __syncthreads();
    int e = blockIdx.x * 256 + threadIdx.x;
    if (e >= E) return;
    int eo = perm ? perm[e] : e;
    float a0 = ea[(size_t)eo * KIN + 0];
    float a1 = ea[(size_t)eo * KIN + 1];
    float a2 = ea[(size_t)eo * KIN + 2];
    float a3 = ea[(size_t)eo * KIN + 3];
    float a4 = ea[(size_t)eo * KIN + 4];
    float a5 = ea[(size_t)eo * KIN + 5];
    float t[KW];
#pragma unroll
    for (int j = 0; j < KW; j++) {
        float s = sb1[j];
        s += a0 * sw1[0 * KW + j];
        s += a1 * sw1[1 * KW + j];
        s += a2 * sw1[2 * KW + j];
        s += a3 * sw1[3 * KW + j];
        s += a4 * sw1[4 * KW + j];
        s += a5 * sw1[5 * KW + j];
        t[j] = fmaxf(s, 0.0f);
    }
    // layer 2 in two halves of 32 outputs (register pressure)
#pragma unroll
    for (int h = 0; h < 2; h++) {
        int j0 = h * 32;
        float4 acc[8];
#pragma unroll
        for (int jj = 0; jj < 8; jj++)
            acc[jj] = *(const float4*)&sb2[j0 + jj * 4];
#pragma unroll
        for (int c = 0; c < KW; c++) {
            float tc = t[c];
#pragma unroll
            for (int jj = 0; jj < 8; jj++) {
                float4 w = *(const float4*)&sw2[c * KW + j0 + jj * 4];
                acc[jj].x += tc * w.x; acc[jj].y += tc * w.y;
                acc[jj].z += tc * w.z; acc[jj].w += tc * w.w;
            }
        }
#pragma unroll
        for (int jj = 0; jj < 8; jj++) {
            float4 r = acc[jj];
            r.x = fmaxf(r.x, 0.f); r.y = fmaxf(r.y, 0.f);
            r.z = fmaxf(r.z, 0.f); r.w = fmaxf(r.w, 0.f);
            *(float4*)&K[(size_t)e * KW + j0 + jj * 4] = r;
        }
    }
}

// ---------------- fused per-depth sweep ----------------
// Block owns NB=8 nodes: phase A computes G rows (8 x 2080) in LDS
// (G[r][c*32+o] = sum_i h[r][i] * M[i][c*32+o]); phase B walks the block's
// src-sorted edge range computing msg = sum_c K[e][c]*G[src][c*32+o] (+bias col)
// and atomically mean-aggregating into agg[dst].

__global__ __launch_bounds__(256, 2) void k_fuse(const int* __restrict__ src_s,
        const int* __restrict__ dst_s, const int* __restrict__ off,
        const float* __restrict__ Ks, const float* __restrict__ M,
        const float* __restrict__ h, float* __restrict__ agg) {
    __shared__ float sG[NB * GROW];   // 66.7 KB
    __shared__ float sHt[32 * NB];    // [k][r]
    int n0 = blockIdx.x * NB;
    int t = threadIdx.x;
    // stage h rows transposed: sHt[k*8 + r]
    {
        int r = t >> 5, k = t & 31;
        sHt[k * NB + r] = h[(size_t)(n0 + r) * WID + k];
    }
    __syncthreads();
    // phase A: G = H @ M, each thread computes one float4-column for all 8 rows
#pragma unroll
    for (int c0 = 0; c0 < GC; c0 += 1024) {
        int col = c0 + t * 4;
        if (col < GC) {
            float4 acc[NB];
#pragma unroll
            for (int r = 0; r < NB; r++) acc[r] = make_float4(0.f, 0.f, 0.f, 0.f);
#pragma unroll
            for (int k = 0; k < 32; k++) {
                float4 mv = *(const float4*)&M[(size_t)k * GC + col];
                float4 h03 = *(const float4*)&sHt[k * NB + 0];
                float4 h47 = *(const float4*)&sHt[k * NB + 4];
                float hr[NB] = {h03.x, h03.y, h03.z, h03.w, h47.x, h47.y, h47.z, h47.w};
#pragma unroll
                for (int r = 0; r < NB; r++) {
                    acc[r].x += hr[r] * mv.x; acc[r].y += hr[r] * mv.y;
                    acc[r].z += hr[r] * mv.z; acc[r].w += hr[r] * mv.w;
                }
            }
#pragma unroll
            for (int r = 0; r < NB; r++)
                *(float4*)&sG[r * GROW + col] = acc[r];
        }
    }
    __syncthreads();
    // phase B: edges [off[n0], off[n0+NB]) — 32 groups of 8 lanes, 1 edge/group
    int e_lo = off[n0];
    int e_hi = off[n0 + NB];
    int g = t >> 3;
    int q4 = (t & 7) * 4;
    for (int e = e_lo + g; e < e_hi; e += 32) {
        int row = src_s[e] - n0;
        int dst = dst_s[e];
        const float* Kr = Ks + (size_t)e * KW;
        int gb = row * GROW;
        float4 a0 = *(const float4*)&sG[gb + 2048 + q4];   // bias-fold column
        float4 a1 = make_float4(0.f, 0.f, 0.f, 0.f);
        float4 a2 = a1, a3 = a1;
#pragma unroll
        for (int c4 = 0; c4 < 16; c4++) {
            float4 kv = *(const float4*)&Kr[c4 * 4];
            float4 g0 = *(const float4*)&sG[gb + (c4 * 4 + 0) * 32 + q4];
            float4 g1 = *(const float4*)&sG[gb + (c4 * 4 + 1) * 32 + q4];
            float4 g2 = *(const float4*)&sG[gb + (c4 * 4 + 2) * 32 + q4];
            float4 g3 = *(const float4*)&sG[gb + (c4 * 4 + 3) * 32 + q4];
            a0.x += kv.x * g0.x; a0.y += kv.x * g0.y; a0.z += kv.x * g0.z; a0.w += kv.x * g0.w;
            a1.x += kv.y * g1.x; a1.y += kv.y * g1.y; a1.z += kv.y * g1.z; a1.w += kv.y * g1.w;
            a2.x += kv.z * g2.x; a2.y += kv.z * g2.y; a2.z += kv.z * g2.z; a2.w += kv.z * g2.w;
            a3.x += kv.w * g3.x; a3.y += kv.w * g3.y; a3.z += kv.w * g3.z; a3.w += kv.w * g3.w;
        }
        float4 m;
        m.x = a0.x + a1.x + a2.x + a3.x;
        m.y = a0.y + a1.y + a2.y + a3.y;
        m.z = a0.z + a1.z + a2.z + a3.z;
        m.w = a0.w + a1.w + a2.w + a3.w;
        float* ap = agg + (size_t)dst * WID + q4;
        unsafeAtomicAdd(ap + 0, m.x);
        unsafeAtomicAdd(ap + 1, m.y);
        unsafeAtomicAdd(ap + 2, m.z);
        unsafeAtomicAdd(ap + 3, m.w);
    }
}

// ---------------- node update + output ----------------

__global__ __launch_bounds__(256) void k_node(const float* __restrict__ hin,
        float* __restrict__ hout,
        const float* __restrict__ agg1, const float* __restrict__ aggb,
        const float* __restrict__ inv1, const float* __restrict__ invb,
        const float* __restrict__ h0, const float* __restrict__ rs,
        const float* __restrict__ bs) {
    __shared__ float sR[1024];
    __shared__ float sB[32];
    for (int i = threadIdx.x; i < 1024; i += 256) sR[i] = rs[i];
    if (threadIdx.x < 32) sB[threadIdx.x] = bs[threadIdx.x];
    __syncthreads();
    int t = blockIdx.x * 256 + threadIdx.x;
    if (t >= NN * WID) return;
    int n = t >> 5, j = t & 31;
    float s = agg1[t] * inv1[n] + aggb[t] * invb[n] + sB[j];
    const float* hr = hin + (size_t)n * WID;
#pragma unroll
    for (int i = 0; i < 32; i++) s += hr[i] * sR[i * 32 + j];
    hout[t] = fmaxf(s, 0.0f) + h0[t];
}

__global__ void k_fc2(const float* __restrict__ h, const float* __restrict__ w,
                      const float* __restrict__ b, float* __restrict__ out) {
    int n = blockIdx.x * blockDim.x + threadIdx.x;
    if (n >= NN) return;
    const float4* hv = (const float4*)(h + (size_t)n * WID);
    const float4* wv = (const float4*)w;
    float s = b[0];
#pragma unroll
    for (int q = 0; q < 8; q++) {
        float4 a = hv[q], c = wv[q];
        s += a.x * c.x + a.y * c.y + a.z * c.z + a.w * c.w;
    }
    out[n] = s;
}

// ---------------- launch ----------------

extern "C" void kernel_launch(void* const* d_in, const int* in_sizes, int n_in,
                              void* d_out, int out_size, void* d_ws, size_t ws_size,
                              hipStream_t stream) {
    const float* x    = (const float*)d_in[0];
    const int*   ei   = (const int*)d_in[1];
    const float* ea   = (const float*)d_in[2];
    const int*   eib  = (const int*)d_in[3];
    const float* eab  = (const float*)d_in[4];
    const float* fc1w = (const float*)d_in[5];
    const float* fc1b = (const float*)d_in[6];
    const float* fc2w = (const float*)d_in[7];
    const float* fc2b = (const float*)d_in[8];
    const float* k1w1 = (const float*)d_in[9];
    const float* k1b1 = (const float*)d_in[10];
    const float* k1w2 = (const float*)d_in[11];
    const float* k1b2 = (const float*)d_in[12];
    const float* k1w3 = (const float*)d_in[13];
    const float* k1b3 = (const float*)d_in[14];
    const float* root1= (const float*)d_in[15];
    const float* bias1= (const float*)d_in[16];
    const float* k2w1 = (const float*)d_in[17];
    const float* k2b1 = (const float*)d_in[18];
    const float* k2w2 = (const float*)d_in[19];
    const float* k2b2 = (const float*)d_in[20];
    const float* k2w3 = (const float*)d_in[21];
    const float* k2b3 = (const float*)d_in[22];
    const float* root2= (const float*)d_in[23];
    const float* bias2= (const float*)d_in[24];

    float* p = (float*)d_ws;
    auto alloc = [&](size_t nflt) { float* r = p; p += nflt; return r; };
    float* K1   = alloc((size_t)EM * KW);     // sorted (by src) order
    float* Kb   = alloc((size_t)EBN * KW);
    float* h0   = alloc((size_t)NN * WID);
    float* hA   = alloc((size_t)NN * WID);
    float* hB   = alloc((size_t)NN * WID);
    float* agg1 = alloc((size_t)NN * WID);
    float* aggb = alloc((size_t)NN * WID);
    float* inv1 = alloc(NN);
    float* invb = alloc(NN);
    float* rs   = alloc(1024);
    float* bs   = alloc(32);
    int*   cnt1 = (int*)alloc(NN);
    int*   cntb = (int*)alloc(NN);
    int*   cs1  = (int*)alloc(NN);
    int*   csb  = (int*)alloc(NN);
    int*   cur1 = (int*)alloc(NN);
    int*   curb = (int*)alloc(NN);
    int*   off1 = (int*)alloc(NN + 2);
    int*   offb = (int*)alloc(NN + 2);
    int*   perm1= (int*)alloc(EM);
    int*   permb= (int*)alloc(EBN);
    int*   srcs1= (int*)alloc(EM);
    int*   dsts1= (int*)alloc(EM);
    int*   srcsb= (int*)alloc(EBN);
    int*   dstsb= (int*)alloc(EBN);
    float* M1   = alloc(32 * GC);
    float* M2   = alloc(32 * GC);

    hipMemsetAsync(cnt1, 0, NN * sizeof(int), stream);
    hipMemsetAsync(cntb, 0, NN * sizeof(int), stream);
    hipMemsetAsync(cs1, 0, NN * sizeof(int), stream);
    hipMemsetAsync(csb, 0, NN * sizeof(int), stream);
    k_prep<<<1, 1024, 0, stream>>>(root1, bias1, root2, bias2, rs, bs);
    k_h0<<<(NN * WID + 255) / 256, 256, 0, stream>>>(x, fc1w, fc1b, h0, hA);
    k_count<<<(EM + 255) / 256, 256, 0, stream>>>(ei + EM, EM, cnt1);     // dst counts
    k_count<<<(EBN + 255) / 256, 256, 0, stream>>>(eib + EBN, EBN, cntb);
    k_inv<<<(NN + 255) / 256, 256, 0, stream>>>(cnt1, inv1, NN);
    k_inv<<<(NN + 255) / 256, 256, 0, stream>>>(cntb, invb, NN);
    k_count<<<(EM + 255) / 256, 256, 0, stream>>>(ei, EM, cs1);           // src counts
    k_count<<<(EBN + 255) / 256, 256, 0, stream>>>(eib, EBN, csb);
    k_scan<<<1, 1024, 0, stream>>>(cs1, cur1, off1, NN);
    k_scan<<<1, 1024, 0, stream>>>(csb, curb, offb, NN);
    k_scatter<<<(EM + 255) / 256, 256, 0, stream>>>(ei, EM, cur1, perm1);
    k_scatter<<<(EBN + 255) / 256, 256, 0, stream>>>(eib, EBN, curb, permb);
    k_permidx<<<(EM + 255) / 256, 256, 0, stream>>>(ei, EM, perm1, srcs1, dsts1);
    k_permidx<<<(EBN + 255) / 256, 256, 0, stream>>>(eib, EBN, permb, srcsb, dstsb);
    k_mlp<<<(EM + 255) / 256, 256, 0, stream>>>(ea, EM, k1w1, k1b1, k1w2, k1b2, perm1, K1);
    k_mlp<<<(EBN + 255) / 256, 256, 0, stream>>>(eab, EBN, k2w1, k2b1, k2w2, k2b2, permb, Kb);
    k_permM<<<(32 * GC + 255) / 256, 256, 0, stream>>>(k1w3, k1b3, M1);
    k_permM<<<(32 * GC + 255) / 256, 256, 0, stream>>>(k2w3, k2b3, M2);

    const float* hin = hA;
    float* hout = hB;
    for (int d = 0; d < NDEPTH; d++) {
        hipMemsetAsync(agg1, 0, (size_t)NN * WID * sizeof(float), stream);
        hipMemsetAsync(aggb, 0, (size_t)NN * WID * sizeof(float), stream);
        k_fuse<<<NN / NB, 256, 0, stream>>>(srcs1, dsts1, off1, K1, M1, hin, agg1);
        k_fuse<<<NN / NB, 256, 0, stream>>>(srcsb, dstsb, offb, Kb, M2, hin, aggb);
        k_node<<<(NN * WID + 255) / 256, 256, 0, stream>>>(hin, hout, agg1, aggb,
                                                           inv1, invb, h0, rs, bs);
        float* tmp = (float*)hin; hin = hout; hout = tmp;
    }
    k_fc2<<<(NN + 255) / 256, 256, 0, stream>>>(hin, fc2w, fc2b, (float*)d_out);
}